// Round 1
// baseline (875.099 us; speedup 1.0000x reference)
//
#include <hip/hip_runtime.h>

#define KCODES 16384
#define CDIM   32
#define NROWS  8192
#define RPB    32      // rows per block
#define KT     256     // codes per K-tile

// workspace layout (floats)
#define WS_MSE   0
#define WS_PLP   1
#define WS_AVGP  16
#define WS_ENORM (16 + KCODES)
#define WS_LSE   (16 + 2*KCODES)

// output layout (floats): z_q [0, N*C), loss [N*C], idx [N*C+1, N*C+1+N)
#define OUT_LOSS (NROWS*CDIM)
#define OUT_IDX  (NROWS*CDIM + 1)

__global__ __launch_bounds__(256) void prep_kernel(const float* __restrict__ emb,
                                                   float* __restrict__ ws) {
  int k = blockIdx.x * 256 + threadIdx.x;            // grid = 64 blocks -> k < 16384 always
  const float4* p = (const float4*)(emb + (size_t)k * CDIM);
  float s = 0.f;
#pragma unroll
  for (int i = 0; i < 8; ++i) {
    float4 v = p[i];
    s += v.x*v.x + v.y*v.y + v.z*v.z + v.w*v.w;
  }
  ws[WS_ENORM + k] = s;
}

// ---------------------------------------------------------------------------
// pass1: distances + online softmax stats + argmin; writes lse, idx, z_q out,
// and accumulates sum(p*logp) and MSE.
// block: 32 rows, loops all K in tiles of KT. thread tile: 4 rows x 8 codes.
// ---------------------------------------------------------------------------
__global__ __launch_bounds__(256) void pass1_kernel(const float* __restrict__ z,
                                                    const float* __restrict__ emb,
                                                    float* __restrict__ ws,
                                                    float* __restrict__ out) {
  __shared__ float  zs[RPB][CDIM];       // z tile, row-major
  __shared__ float  znorm_s[RPB];
  __shared__ float2 es[KT][17];          // 16 float2 of e-row + [16].x = enorm; stride 34 floats
  __shared__ int    idx_s[RPB];

  const int tid = threadIdx.x;
  const int n0  = blockIdx.x * RPB;
  const int b   = n0 >> 8;               // 256 rows per batch image
  const int hw0 = n0 & 255;

  // stage z tile: rows n0..n0+31 all share the same b; z[b][c][hw]
  {
    int c  = tid >> 3;                   // 0..31
    int i0 = (tid & 7) * 4;              // 0,4,...,28
    const float4 v = *(const float4*)(z + (size_t)b*8192 + c*256 + hw0 + i0);
    zs[i0+0][c] = v.x; zs[i0+1][c] = v.y; zs[i0+2][c] = v.z; zs[i0+3][c] = v.w;
  }
  __syncthreads();
  if (tid < RPB) {
    float s = 0.f;
#pragma unroll
    for (int c = 0; c < CDIM; ++c) s += zs[tid][c]*zs[tid][c];
    znorm_s[tid] = s;
  }
  __syncthreads();

  const int rg = tid >> 5;               // 0..7  -> rows rg*4..rg*4+3
  const int cg = tid & 31;               // codes cg + 32*j (strided -> conflict-free LDS)

  float zn[4];
#pragma unroll
  for (int r = 0; r < 4; ++r) zn[r] = znorm_s[rg*4 + r];

  // online softmax state in logit domain l = -100*d  (max l == min d)
  float m[4], s[4], tt[4];               // tt = sum e^(l-m) * (l-m)
  int   imin[4];
#pragma unroll
  for (int r = 0; r < 4; ++r) { m[r] = -3.0e38f; s[r] = 0.f; tt[r] = 0.f; imin[r] = 0; }

  const float* enorm = ws + WS_ENORM;

  for (int k0 = 0; k0 < KCODES; k0 += KT) {
    // stage e tile (coalesced: 4 threads per code row, 2 float4 each)
#pragma unroll
    for (int w = 0; w < 4; ++w) {
      int kk = (tid >> 2) + 64*w;
      int c4 = tid & 3;
#pragma unroll
      for (int h = 0; h < 2; ++h) {
        int cc = c4 + 4*h;
        const float4 v = *(const float4*)(emb + (size_t)(k0+kk)*CDIM + cc*4);
        es[kk][cc*2+0] = make_float2(v.x, v.y);
        es[kk][cc*2+1] = make_float2(v.z, v.w);
      }
    }
    es[tid][16].x = enorm[k0 + tid];
    __syncthreads();

    float acc[4][8];
#pragma unroll
    for (int r = 0; r < 4; ++r)
#pragma unroll
      for (int j = 0; j < 8; ++j) acc[r][j] = 0.f;

#pragma unroll
    for (int c4 = 0; c4 < 8; ++c4) {
      float4 zv[4];
#pragma unroll
      for (int r = 0; r < 4; ++r) zv[r] = *(const float4*)(&zs[rg*4 + r][c4*4]);
#pragma unroll
      for (int j = 0; j < 8; ++j) {
        float2 e0 = es[cg + 32*j][c4*2 + 0];
        float2 e1 = es[cg + 32*j][c4*2 + 1];
#pragma unroll
        for (int r = 0; r < 4; ++r) {
          acc[r][j] = fmaf(zv[r].x, e0.x, acc[r][j]);
          acc[r][j] = fmaf(zv[r].y, e0.y, acc[r][j]);
          acc[r][j] = fmaf(zv[r].z, e1.x, acc[r][j]);
          acc[r][j] = fmaf(zv[r].w, e1.y, acc[r][j]);
        }
      }
    }

    // online stats update (codes processed in increasing index order -> first-min tie-break)
#pragma unroll
    for (int j = 0; j < 8; ++j) {
      int   kl   = cg + 32*j;
      float en   = es[kl][16].x;
      int   code = k0 + kl;
#pragma unroll
      for (int r = 0; r < 4; ++r) {
        float v = fmaf(-2.f, acc[r][j], zn[r] + en);   // d(n,k)
        float l = -100.f * v;
        if (l > m[r]) {                                 // strictly better min-distance
          float d0 = m[r] - l;
          float a  = __expf(d0);
          tt[r] = a * (tt[r] + d0 * s[r]);
          s[r]  = fmaf(s[r], a, 1.f);
          m[r]  = l; imin[r] = code;
        } else {
          float u = l - m[r];
          if (u > -104.f) {                             // below: exp underflows to 0 exactly
            float e = __expf(u);
            s[r] += e; tt[r] = fmaf(e, u, tt[r]);
          }
        }
      }
    }
    __syncthreads();
  }

  // reduce (m,s,tt,imin) across the 32 cg lanes (butterfly stays within 32-lane half-wave)
#pragma unroll
  for (int r = 0; r < 4; ++r) {
    float mm = m[r], ss = s[r], tr = tt[r];
    int   ii = imin[r];
    for (int off = 1; off < 32; off <<= 1) {
      float mo = __shfl_xor(mm, off);
      float so = __shfl_xor(ss, off);
      float to = __shfl_xor(tr, off);
      int   io = __shfl_xor(ii, off);
      float M  = fmaxf(mm, mo);
      float a  = __expf(mm - M);
      float bb = __expf(mo - M);
      tr = a*(tr + (mm - M)*ss) + bb*(to + (mo - M)*so);
      ss = a*ss + bb*so;
      ii = (mo > mm || (mo == mm && io < ii)) ? io : ii;
      mm = M;
    }
    if (cg == 0) {
      int n = n0 + rg*4 + r;
      float ls = __logf(ss);
      ws[WS_LSE + n] = mm + ls;                 // logsumexp in l-domain
      atomicAdd(&ws[WS_PLP], tr/ss - ls);       // sum_k p*logp for this row
      out[OUT_IDX + n] = (float)ii;
      idx_s[rg*4 + r] = ii;
    }
  }
  __syncthreads();

  // epilogue: z_q gather + straight-through output + MSE
  float msel = 0.f;
#pragma unroll
  for (int q = 0; q < 4; ++q) {
    int c = (tid >> 5) + 8*q;                   // 0..31
    int i = tid & 31;                           // local row
    float zq = emb[(size_t)idx_s[i]*CDIM + c];
    float zf = zs[i][c];
    float dd = zq - zf;
    msel += dd*dd;
    out[(size_t)b*8192 + c*256 + hw0 + i] = zf + (zq - zf);  // match ref op order
  }
  for (int off = 1; off < 64; off <<= 1) msel += __shfl_xor(msel, off);
  if ((tid & 63) == 0) atomicAdd(&ws[WS_MSE], msel);
}

// ---------------------------------------------------------------------------
// pass2: recompute l, p = exp(l - lse), accumulate avg_probs[k] (atomic, skip zeros)
// ---------------------------------------------------------------------------
__global__ __launch_bounds__(256) void pass2_kernel(const float* __restrict__ z,
                                                    const float* __restrict__ emb,
                                                    float* __restrict__ ws) {
  __shared__ float  zs[RPB][CDIM];
  __shared__ float  znorm_s[RPB];
  __shared__ float2 es[KT][17];

  const int tid = threadIdx.x;
  const int n0  = blockIdx.x * RPB;
  const int b   = n0 >> 8;
  const int hw0 = n0 & 255;

  {
    int c  = tid >> 3;
    int i0 = (tid & 7) * 4;
    const float4 v = *(const float4*)(z + (size_t)b*8192 + c*256 + hw0 + i0);
    zs[i0+0][c] = v.x; zs[i0+1][c] = v.y; zs[i0+2][c] = v.z; zs[i0+3][c] = v.w;
  }
  __syncthreads();
  if (tid < RPB) {
    float s = 0.f;
#pragma unroll
    for (int c = 0; c < CDIM; ++c) s += zs[tid][c]*zs[tid][c];
    znorm_s[tid] = s;
  }
  __syncthreads();

  const int rg = tid >> 5;
  const int cg = tid & 31;

  float zn[4], lse_r[4];
#pragma unroll
  for (int r = 0; r < 4; ++r) {
    zn[r]    = znorm_s[rg*4 + r];
    lse_r[r] = ws[WS_LSE + n0 + rg*4 + r];
  }

  const float* enorm = ws + WS_ENORM;

  for (int k0 = 0; k0 < KCODES; k0 += KT) {
#pragma unroll
    for (int w = 0; w < 4; ++w) {
      int kk = (tid >> 2) + 64*w;
      int c4 = tid & 3;
#pragma unroll
      for (int h = 0; h < 2; ++h) {
        int cc = c4 + 4*h;
        const float4 v = *(const float4*)(emb + (size_t)(k0+kk)*CDIM + cc*4);
        es[kk][cc*2+0] = make_float2(v.x, v.y);
        es[kk][cc*2+1] = make_float2(v.z, v.w);
      }
    }
    es[tid][16].x = enorm[k0 + tid];
    __syncthreads();

    float acc[4][8];
#pragma unroll
    for (int r = 0; r < 4; ++r)
#pragma unroll
      for (int j = 0; j < 8; ++j) acc[r][j] = 0.f;

#pragma unroll
    for (int c4 = 0; c4 < 8; ++c4) {
      float4 zv[4];
#pragma unroll
      for (int r = 0; r < 4; ++r) zv[r] = *(const float4*)(&zs[rg*4 + r][c4*4]);
#pragma unroll
      for (int j = 0; j < 8; ++j) {
        float2 e0 = es[cg + 32*j][c4*2 + 0];
        float2 e1 = es[cg + 32*j][c4*2 + 1];
#pragma unroll
        for (int r = 0; r < 4; ++r) {
          acc[r][j] = fmaf(zv[r].x, e0.x, acc[r][j]);
          acc[r][j] = fmaf(zv[r].y, e0.y, acc[r][j]);
          acc[r][j] = fmaf(zv[r].z, e1.x, acc[r][j]);
          acc[r][j] = fmaf(zv[r].w, e1.y, acc[r][j]);
        }
      }
    }

#pragma unroll
    for (int j = 0; j < 8; ++j) {
      int   kl = cg + 32*j;
      float en = es[kl][16].x;
      float pj = 0.f;
#pragma unroll
      for (int r = 0; r < 4; ++r) {
        float v = fmaf(-2.f, acc[r][j], zn[r] + en);
        float l = -100.f * v;
        float u = l - lse_r[r];
        if (u > -104.f) pj += __expf(u);
      }
      if (pj != 0.f) atomicAdd(&ws[WS_AVGP + k0 + kl], pj);
    }
    __syncthreads();
  }
}

__global__ __launch_bounds__(256) void finalize_kernel(const float* __restrict__ ws,
                                                       float* __restrict__ out) {
  __shared__ float red[256];
  float h = 0.f;
  for (int k = threadIdx.x; k < KCODES; k += 256) {
    float ap = ws[WS_AVGP + k] * (1.f/8192.f);
    h += ap * __logf(ap + 1e-5f);
  }
  red[threadIdx.x] = h;
  __syncthreads();
  for (int st = 128; st > 0; st >>= 1) {
    if (threadIdx.x < st) red[threadIdx.x] += red[threadIdx.x + st];
    __syncthreads();
  }
  if (threadIdx.x == 0) {
    float mse        = ws[WS_MSE] * (1.f/(8192.f*32.f));
    float sample_ent = -ws[WS_PLP] * (1.f/8192.f);
    // avg_entropy = -red[0]; ent_loss = sample_ent - avg_entropy = sample_ent + red[0]
    out[OUT_LOSS] = 1.25f*mse + 0.1f*(sample_ent + red[0]);
  }
}

extern "C" void kernel_launch(void* const* d_in, const int* in_sizes, int n_in,
                              void* d_out, int out_size, void* d_ws, size_t ws_size,
                              hipStream_t stream) {
  (void)in_sizes; (void)n_in; (void)out_size; (void)ws_size;
  const float* z   = (const float*)d_in[0];
  const float* emb = (const float*)d_in[1];
  float* out = (float*)d_out;
  float* ws  = (float*)d_ws;

  // zero scalar accumulators + avg_probs ( [0, WS_ENORM) )
  hipMemsetAsync(ws, 0, (size_t)WS_ENORM * sizeof(float), stream);

  prep_kernel<<<KCODES/256, 256, 0, stream>>>(emb, ws);
  pass1_kernel<<<NROWS/RPB, 256, 0, stream>>>(z, emb, ws, out);
  pass2_kernel<<<NROWS/RPB, 256, 0, stream>>>(z, emb, ws);
  finalize_kernel<<<1, 256, 0, stream>>>(ws, out);
}

// Round 2
// 819.364 us; speedup vs baseline: 1.0680x; 1.0680x over previous
//
#include <hip/hip_runtime.h>

#define KCODES 16384
#define CDIM   32
#define NROWS  8192
#define RPB    32                 // rows per block
#define KT     256                // codes per K-tile
#define KSPLIT 4                  // K-chunks (blocks per row-group)
#define CHUNK  (KCODES/KSPLIT)    // 4096
#define TILES  (CHUNK/KT)         // 16
#define CUT    -35.0f             // exp cutoff: exp(-35)=6e-16, invisible vs +1e-5 in logs

// workspace layout (floats)
#define WS_MSE   0
#define WS_PLP   1
#define WS_AVGP  16
#define WS_ENORM (16 + KCODES)
#define WS_LSE   (16 + 2*KCODES)
#define WS_PART  (16 + 2*KCODES + NROWS)   // byte offset 163904, 16B-aligned -> float4 ok

// output layout (floats): z_q [0, N*C), loss [N*C], idx [N*C+1, ...)
#define OUT_LOSS (NROWS*CDIM)
#define OUT_IDX  (NROWS*CDIM + 1)

__global__ __launch_bounds__(256) void prep_kernel(const float* __restrict__ emb,
                                                   float* __restrict__ ws) {
  int k = blockIdx.x * 256 + threadIdx.x;
  const float4* p = (const float4*)(emb + (size_t)k * CDIM);
  float s = 0.f;
#pragma unroll
  for (int i = 0; i < 8; ++i) {
    float4 v = p[i];
    s += v.x*v.x + v.y*v.y + v.z*v.z + v.w*v.w;
  }
  ws[WS_ENORM + k] = s;
}

// ---------------------------------------------------------------------------
// pass1_part: block = (rowgroup, chunk). 32 rows x 4096 codes.
// Online softmax (m,s,tt) + argmin over the chunk; lane-reduced partial
// written as float4(m, s, tt, idx_bits) to ws_part[chunk][row].
// ---------------------------------------------------------------------------
__global__ __launch_bounds__(256) void pass1_part(const float* __restrict__ z,
                                                  const float* __restrict__ emb,
                                                  const float* __restrict__ ws,
                                                  float4* __restrict__ part) {
  __shared__ float  zs[RPB][36];      // stride 36: 16B-aligned rows, bank-spread
  __shared__ float  znorm_s[RPB];
  __shared__ float4 es4[KT][9];       // stride 9 float4: bank-group spread
  __shared__ float  es_n[KT];

  const int tid   = threadIdx.x;
  const int n0    = blockIdx.x * RPB;
  const int kbase = blockIdx.y * CHUNK;
  const int b     = n0 >> 8;
  const int hw0   = n0 & 255;

  { // stage z tile (rows share the same b)
    int c  = tid >> 3;
    int i0 = (tid & 7) * 4;
    const float4 v = *(const float4*)(z + (size_t)b*8192 + c*256 + hw0 + i0);
    zs[i0+0][c] = v.x; zs[i0+1][c] = v.y; zs[i0+2][c] = v.z; zs[i0+3][c] = v.w;
  }
  __syncthreads();
  if (tid < RPB) {
    float s = 0.f;
#pragma unroll
    for (int c = 0; c < CDIM; ++c) s += zs[tid][c]*zs[tid][c];
    znorm_s[tid] = s;
  }
  __syncthreads();

  const int rg = tid >> 5;            // rows rg*4 .. rg*4+3
  const int cg = tid & 31;            // codes cg + 32*j

  float zn[4];
#pragma unroll
  for (int r = 0; r < 4; ++r) zn[r] = znorm_s[rg*4 + r];

  float m[4], s[4], tt[4];
  int   imin[4];
#pragma unroll
  for (int r = 0; r < 4; ++r) { m[r] = -3.0e38f; s[r] = 0.f; tt[r] = 0.f; imin[r] = kbase; }

  const float4* emb4  = (const float4*)emb;
  const float*  enorm = ws + WS_ENORM;

  for (int t = 0; t < TILES; ++t) {
    const int k0 = kbase + t*KT;
    // stage e tile: 2048 float4 / 256 threads = 8 each, fully coalesced
#pragma unroll
    for (int w = 0; w < 8; ++w) {
      int g  = tid + 256*w;
      int kk = g >> 3, c4 = g & 7;
      es4[kk][c4] = emb4[(size_t)(k0 + kk)*8 + c4];
    }
    es_n[tid] = enorm[k0 + tid];
    __syncthreads();

    float acc[4][8];
#pragma unroll
    for (int r = 0; r < 4; ++r)
#pragma unroll
      for (int j = 0; j < 8; ++j) acc[r][j] = 0.f;

#pragma unroll
    for (int c4 = 0; c4 < 8; ++c4) {
      float4 zv[4];
#pragma unroll
      for (int r = 0; r < 4; ++r) zv[r] = *(const float4*)(&zs[rg*4 + r][c4*4]);
#pragma unroll
      for (int j = 0; j < 8; ++j) {
        float4 ev = es4[cg + 32*j][c4];
#pragma unroll
        for (int r = 0; r < 4; ++r) {
          acc[r][j] = fmaf(zv[r].x, ev.x, acc[r][j]);
          acc[r][j] = fmaf(zv[r].y, ev.y, acc[r][j]);
          acc[r][j] = fmaf(zv[r].z, ev.z, acc[r][j]);
          acc[r][j] = fmaf(zv[r].w, ev.w, acc[r][j]);
        }
      }
    }

    // online stats (codes ascending -> first-min tie-break, same as round 1)
#pragma unroll
    for (int j = 0; j < 8; ++j) {
      int   kl   = cg + 32*j;
      float en   = es_n[kl];
      int   code = k0 + kl;
#pragma unroll
      for (int r = 0; r < 4; ++r) {
        float v = fmaf(-2.f, acc[r][j], zn[r] + en);   // d(n,k)
        float l = -100.f * v;
        if (l > m[r]) {
          float d0 = m[r] - l;
          float a  = __expf(d0);
          tt[r] = a * (tt[r] + d0 * s[r]);
          s[r]  = fmaf(s[r], a, 1.f);
          m[r]  = l; imin[r] = code;
        } else {
          float u = l - m[r];
          if (u > CUT) {
            float e = __expf(u);
            s[r] += e; tt[r] = fmaf(e, u, tt[r]);
          }
        }
      }
    }
    __syncthreads();
  }

  // reduce across the 32 cg lanes, write partial
#pragma unroll
  for (int r = 0; r < 4; ++r) {
    float mm = m[r], ss = s[r], tr = tt[r];
    int   ii = imin[r];
    for (int off = 1; off < 32; off <<= 1) {
      float mo = __shfl_xor(mm, off);
      float so = __shfl_xor(ss, off);
      float to = __shfl_xor(tr, off);
      int   io = __shfl_xor(ii, off);
      float M  = fmaxf(mm, mo);
      float a  = __expf(mm - M);
      float bb = __expf(mo - M);
      tr = a*(tr + (mm - M)*ss) + bb*(to + (mo - M)*so);
      ss = a*ss + bb*so;
      ii = (mo > mm || (mo == mm && io < ii)) ? io : ii;
      mm = M;
    }
    if (cg == 0)
      part[(size_t)blockIdx.y*NROWS + n0 + rg*4 + r] =
          make_float4(mm, ss, tr, __int_as_float(ii));
  }
}

// ---------------------------------------------------------------------------
// combine: merge KSPLIT partials per row -> lse, idx, plp
// ---------------------------------------------------------------------------
__global__ __launch_bounds__(256) void combine_kernel(const float4* __restrict__ part,
                                                      float* __restrict__ ws,
                                                      float* __restrict__ out) {
  int n = blockIdx.x*256 + threadIdx.x;
  float4 p0 = part[n];
  float mm = p0.x, ss = p0.y, tr = p0.z;
  int   ii = __float_as_int(p0.w);
#pragma unroll
  for (int c = 1; c < KSPLIT; ++c) {
    float4 pc = part[(size_t)c*NROWS + n];
    float mo = pc.x, so = pc.y, to = pc.z;
    int   io = __float_as_int(pc.w);
    float M  = fmaxf(mm, mo);
    float a  = __expf(mm - M);
    float bb = __expf(mo - M);
    tr = a*(tr + (mm - M)*ss) + bb*(to + (mo - M)*so);
    ss = a*ss + bb*so;
    if (mo > mm) ii = io;          // ties keep earlier chunk (lower index)
    mm = M;
  }
  float ls = __logf(ss);
  ws[WS_LSE + n] = mm + ls;
  out[OUT_IDX + n] = (float)ii;
  float plp = tr/ss - ls;
  for (int off = 1; off < 64; off <<= 1) plp += __shfl_xor(plp, off);
  if ((threadIdx.x & 63) == 0) atomicAdd(&ws[WS_PLP], plp);
}

// ---------------------------------------------------------------------------
// zq epilogue: straight-through output + MSE
// ---------------------------------------------------------------------------
__global__ __launch_bounds__(256) void zq_kernel(const float* __restrict__ z,
                                                 const float* __restrict__ emb,
                                                 float* __restrict__ ws,
                                                 float* __restrict__ out) {
  int f  = blockIdx.x*256 + threadIdx.x;   // f = b*8192 + c*256 + hw
  int hw = f & 255;
  int c  = (f >> 8) & 31;
  int b  = f >> 13;
  int n  = b*256 + hw;
  int idx = (int)out[OUT_IDX + n];
  float zq = emb[(size_t)idx*CDIM + c];
  float zf = z[f];
  out[f] = zf + (zq - zf);
  float d = zq - zf;
  float msel = d*d;
  for (int off = 1; off < 64; off <<= 1) msel += __shfl_xor(msel, off);
  if ((threadIdx.x & 63) == 0) atomicAdd(&ws[WS_MSE], msel);
}

// ---------------------------------------------------------------------------
// pass2_part: recompute logits, p = exp(l - lse); per-tile LDS accumulation of
// avg_probs, then <=1 global atomic per code per block.
// ---------------------------------------------------------------------------
__global__ __launch_bounds__(256) void pass2_part(const float* __restrict__ z,
                                                  const float* __restrict__ emb,
                                                  float* __restrict__ ws) {
  __shared__ float  zs[RPB][36];
  __shared__ float  znorm_s[RPB];
  __shared__ float4 es4[KT][9];
  __shared__ float  es_n[KT];
  __shared__ float  avg_t[KT];

  const int tid   = threadIdx.x;
  const int n0    = blockIdx.x * RPB;
  const int kbase = blockIdx.y * CHUNK;
  const int b     = n0 >> 8;
  const int hw0   = n0 & 255;

  {
    int c  = tid >> 3;
    int i0 = (tid & 7) * 4;
    const float4 v = *(const float4*)(z + (size_t)b*8192 + c*256 + hw0 + i0);
    zs[i0+0][c] = v.x; zs[i0+1][c] = v.y; zs[i0+2][c] = v.z; zs[i0+3][c] = v.w;
  }
  __syncthreads();
  if (tid < RPB) {
    float s = 0.f;
#pragma unroll
    for (int c = 0; c < CDIM; ++c) s += zs[tid][c]*zs[tid][c];
    znorm_s[tid] = s;
  }
  __syncthreads();

  const int rg = tid >> 5;
  const int cg = tid & 31;

  float zn[4], lse_r[4];
#pragma unroll
  for (int r = 0; r < 4; ++r) {
    zn[r]    = znorm_s[rg*4 + r];
    lse_r[r] = ws[WS_LSE + n0 + rg*4 + r];
  }

  const float4* emb4  = (const float4*)emb;
  const float*  enorm = ws + WS_ENORM;

  for (int t = 0; t < TILES; ++t) {
    const int k0 = kbase + t*KT;
    avg_t[tid] = 0.f;
#pragma unroll
    for (int w = 0; w < 8; ++w) {
      int g  = tid + 256*w;
      int kk = g >> 3, c4 = g & 7;
      es4[kk][c4] = emb4[(size_t)(k0 + kk)*8 + c4];
    }
    es_n[tid] = enorm[k0 + tid];
    __syncthreads();

    float acc[4][8];
#pragma unroll
    for (int r = 0; r < 4; ++r)
#pragma unroll
      for (int j = 0; j < 8; ++j) acc[r][j] = 0.f;

#pragma unroll
    for (int c4 = 0; c4 < 8; ++c4) {
      float4 zv[4];
#pragma unroll
      for (int r = 0; r < 4; ++r) zv[r] = *(const float4*)(&zs[rg*4 + r][c4*4]);
#pragma unroll
      for (int j = 0; j < 8; ++j) {
        float4 ev = es4[cg + 32*j][c4];
#pragma unroll
        for (int r = 0; r < 4; ++r) {
          acc[r][j] = fmaf(zv[r].x, ev.x, acc[r][j]);
          acc[r][j] = fmaf(zv[r].y, ev.y, acc[r][j]);
          acc[r][j] = fmaf(zv[r].z, ev.z, acc[r][j]);
          acc[r][j] = fmaf(zv[r].w, ev.w, acc[r][j]);
        }
      }
    }

#pragma unroll
    for (int j = 0; j < 8; ++j) {
      int   kl = cg + 32*j;
      float en = es_n[kl];
      float pj = 0.f;
#pragma unroll
      for (int r = 0; r < 4; ++r) {
        float v = fmaf(-2.f, acc[r][j], zn[r] + en);
        float l = -100.f * v;
        float u = l - lse_r[r];
        if (u > CUT) pj += __expf(u);
      }
      if (pj != 0.f) atomicAdd(&avg_t[kl], pj);
    }
    __syncthreads();

    float av = avg_t[tid];
    if (av != 0.f) atomicAdd(&ws[WS_AVGP + k0 + tid], av);
  }
}

__global__ __launch_bounds__(256) void finalize_kernel(const float* __restrict__ ws,
                                                       float* __restrict__ out) {
  __shared__ float red[256];
  float h = 0.f;
  for (int k = threadIdx.x; k < KCODES; k += 256) {
    float ap = ws[WS_AVGP + k] * (1.f/8192.f);
    h += ap * __logf(ap + 1e-5f);
  }
  red[threadIdx.x] = h;
  __syncthreads();
  for (int st = 128; st > 0; st >>= 1) {
    if (threadIdx.x < st) red[threadIdx.x] += red[threadIdx.x + st];
    __syncthreads();
  }
  if (threadIdx.x == 0) {
    float mse        = ws[WS_MSE] * (1.f/(8192.f*32.f));
    float sample_ent = -ws[WS_PLP] * (1.f/8192.f);
    out[OUT_LOSS] = 1.25f*mse + 0.1f*(sample_ent + red[0]);
  }
}

extern "C" void kernel_launch(void* const* d_in, const int* in_sizes, int n_in,
                              void* d_out, int out_size, void* d_ws, size_t ws_size,
                              hipStream_t stream) {
  (void)in_sizes; (void)n_in; (void)out_size; (void)ws_size;
  const float* z   = (const float*)d_in[0];
  const float* emb = (const float*)d_in[1];
  float* out = (float*)d_out;
  float* ws  = (float*)d_ws;
  float4* part = (float4*)(ws + WS_PART);

  hipMemsetAsync(ws, 0, (size_t)(16 + KCODES)*sizeof(float), stream);

  prep_kernel   <<<KCODES/256, 256, 0, stream>>>(emb, ws);
  pass1_part    <<<dim3(NROWS/RPB, KSPLIT), 256, 0, stream>>>(z, emb, ws, part);
  combine_kernel<<<NROWS/256, 256, 0, stream>>>(part, ws, out);
  zq_kernel     <<<(NROWS*CDIM)/256, 256, 0, stream>>>(z, emb, ws, out);
  pass2_part    <<<dim3(NROWS/RPB, KSPLIT), 256, 0, stream>>>(z, emb, ws);
  finalize_kernel<<<1, 256, 0, stream>>>(ws, out);
}